// Round 4
// baseline (180.249 us; speedup 1.0000x reference)
//
#include <hip/hip_runtime.h>
#include <hip/hip_bf16.h>
#include <stdint.h>

#define M_DIM 2048
#define N_DIM 4096
#define K_DIM 4096

typedef __attribute__((ext_vector_type(8))) __bf16 bf16x8;
typedef __attribute__((ext_vector_type(4))) float f32x4;
typedef __attribute__((ext_vector_type(8))) unsigned short u16x8;

__device__ __constant__ float NF4_TAB[16] = {
    -1.0f, -0.6961928009986877f, -0.5250730514526367f, -0.39491748809814453f,
    -0.28444138169288635f, -0.18477343022823334f, -0.09105003625154495f, 0.0f,
    0.07958029955625534f, 0.16093020141124725f, 0.24611230194568634f,
    0.33791524171829224f, 0.44070982933044434f, 0.5626170039176941f,
    0.7229568362236023f, 1.0f};

// fp32 -> bf16 round-to-nearest-even
__device__ inline unsigned short f2b(float f) {
  union { float f; uint32_t u; } v; v.f = f;
  uint32_t u = v.u;
  return (unsigned short)((u + 0x7fffu + ((u >> 16) & 1u)) >> 16);
}

// ---------------- K1: fp32 -> bf16 (generic, used for input / lora_A / lora_B) --
__global__ void k_cvt(const float4* __restrict__ in, ushort4* __restrict__ out, int n) {
  int i = blockIdx.x * 256 + threadIdx.x;
  if (i < n) {
    float4 v = in[i];
    ushort4 o;
    o.x = f2b(v.x); o.y = f2b(v.y); o.z = f2b(v.z); o.w = f2b(v.w);
    out[i] = o;
  }
}

// ---------------- K2: pure NF4 dequant -> bf16 W (N x K), no LoRA --------------
// thread handles 8 consecutive elems = 4 packed int32 = one int4 load, one 16B store.
__global__ void __launch_bounds__(256) k_build_w(const int* __restrict__ qw,
                                                 const float* __restrict__ am,
                                                 unsigned short* __restrict__ W) {
  __shared__ float tab[16];
  const int t = threadIdx.x;
  if (t < 16) tab[t] = NF4_TAB[t];
  __syncthreads();
  size_t i = (size_t)blockIdx.x * 256 + t;        // group of 8 elems
  int4 q = *(const int4*)(qw + i * 4);
  float amv = am[i >> 3];                          // (i*8)/64
  u16x8 o;
  o[0] = f2b(tab[q.x & 15] * amv);  o[1] = f2b(tab[(q.x >> 4) & 15] * amv);
  o[2] = f2b(tab[q.y & 15] * amv);  o[3] = f2b(tab[(q.y >> 4) & 15] * amv);
  o[4] = f2b(tab[q.z & 15] * amv);  o[5] = f2b(tab[(q.z >> 4) & 15] * amv);
  o[6] = f2b(tab[q.w & 15] * amv);  o[7] = f2b(tab[(q.w >> 4) & 15] * amv);
  *(u16x8*)(W + i * 8) = o;
}

// ---------------- K2b: U = A16 @ lora_A16^T  (2048 x 64, K=4096) ---------------
// grid 16 blocks x 256 thr; wave w owns rows m0..m0+31, all 64 cols.
__global__ void __launch_bounds__(256) k_lora_u(const unsigned short* __restrict__ A16,
                                                const unsigned short* __restrict__ lA16,
                                                unsigned short* __restrict__ U) {
  const int ln = threadIdx.x & 63, w = threadIdx.x >> 6;
  const int lr = ln & 15, lk = ln >> 4;
  const int m0 = blockIdx.x * 128 + w * 32;
  f32x4 acc[2][4] = {};
#pragma unroll 2
  for (int kk = 0; kk < K_DIM; kk += 32) {
    bf16x8 af[2], bv[4];
#pragma unroll
    for (int mi = 0; mi < 2; ++mi)
      af[mi] = *(const bf16x8*)(A16 + (size_t)(m0 + mi * 16 + lr) * K_DIM + kk + lk * 8);
#pragma unroll
    for (int ni = 0; ni < 4; ++ni)
      bv[ni] = *(const bf16x8*)(lA16 + (size_t)(ni * 16 + lr) * K_DIM + kk + lk * 8);
#pragma unroll
    for (int mi = 0; mi < 2; ++mi)
#pragma unroll
      for (int ni = 0; ni < 4; ++ni)
        acc[mi][ni] = __builtin_amdgcn_mfma_f32_16x16x32_bf16(af[mi], bv[ni],
                                                              acc[mi][ni], 0, 0, 0);
  }
  // C/D layout: col = lane&15, row = (lane>>4)*4 + reg
#pragma unroll
  for (int mi = 0; mi < 2; ++mi)
#pragma unroll
    for (int ni = 0; ni < 4; ++ni)
#pragma unroll
      for (int r = 0; r < 4; ++r)
        U[(size_t)(m0 + mi * 16 + lk * 4 + r) * 64 + ni * 16 + lr] = f2b(acc[mi][ni][r]);
}

// ---------------- K3: phased bf16 GEMM + rank-64 K-extension -------------------
// BM=128, BN=256, BK=64. 8 waves 2Mx4N, wave tile 64x64. 3 rotating LDS buffers.
// 65 K-tiles: 0..63 from A16/B16 (stride 4096), tile 64 from U/lB16 (stride 64).
#define LDSBUF 24576  // ushorts per buffer: A 128*64 + B 256*64

#define FENCE() asm volatile("" ::: "memory")
#define BAR() do { FENCE(); __builtin_amdgcn_s_barrier(); FENCE(); } while (0)

#define COMPUTE_PHASE(KS, BC)                                                    \
  do {                                                                           \
    bf16x8 af[4], bv[4];                                                         \
    _Pragma("unroll") for (int mi = 0; mi < 4; ++mi) {                           \
      int row = wr * 64 + mi * 16 + lr;                                          \
      int slot = (((KS) << 2) | lk) ^ (row & 7);                                 \
      af[mi] = *(const bf16x8*)((BC) + row * 64 + slot * 8);                     \
    }                                                                            \
    _Pragma("unroll") for (int ni = 0; ni < 4; ++ni) {                           \
      int row = wc * 64 + ni * 16 + lr;                                          \
      int slot = (((KS) << 2) | lk) ^ (row & 7);                                 \
      bv[ni] = *(const bf16x8*)((BC) + 8192 + row * 64 + slot * 8);              \
    }                                                                            \
    __builtin_amdgcn_s_setprio(1);                                               \
    _Pragma("unroll") for (int mi = 0; mi < 4; ++mi)                             \
    _Pragma("unroll") for (int ni = 0; ni < 4; ++ni)                             \
      acc[mi][ni] = __builtin_amdgcn_mfma_f32_16x16x32_bf16(                     \
          af[mi], bv[ni], acc[mi][ni], 0, 0, 0);                                 \
    __builtin_amdgcn_s_setprio(0);                                               \
  } while (0)

__global__ void __launch_bounds__(512, 2) k_gemm(const unsigned short* __restrict__ A,
                                                 const unsigned short* __restrict__ B,
                                                 const unsigned short* __restrict__ U,
                                                 const unsigned short* __restrict__ LB,
                                                 float* __restrict__ C) {
  __shared__ unsigned short lds[3 * LDSBUF];  // 144 KB
  const int tid = threadIdx.x;
  const int ln = tid & 63;
  const int wid = tid >> 6;  // 0..7
  const int wr = wid >> 2;   // 0..1  (M)
  const int wc = wid & 3;    // 0..3  (N)
  const int lr = ln & 15;
  const int lk = ln >> 4;

  const int sw = (blockIdx.x & 7) * 32 + (blockIdx.x >> 3);
  const int bm = sw & 15;
  const int bn = sw >> 4;
  const size_t arow0 = (size_t)bm * 128;
  const size_t brow0 = (size_t)bn * 256;

  const int srow = (wid << 3) + (ln >> 3);
  const int gs0 = (ln & 7) ^ (srow & 7);
  auto stage = [&](const unsigned short* __restrict__ G, size_t stride, size_t grow0,
                   int kt, unsigned short* dst) {
    const char* g = (const char*)(G + (grow0 + srow) * stride) + kt * 128 + gs0 * 16;
    __builtin_amdgcn_global_load_lds(
        (const __attribute__((address_space(1))) uint32_t*)g,
        (__attribute__((address_space(3))) uint32_t*)(dst + (size_t)(wid << 3) * 64),
        16, 0, 0);
  };

  f32x4 acc[4][4] = {};

  // prologue: K-tiles 0,1 (both regular)
  stage(A, K_DIM, arow0, 0, lds);
  stage(A, K_DIM, arow0 + 64, 0, lds + 4096);
  stage(B, K_DIM, brow0, 0, lds + 8192);
  stage(B, K_DIM, brow0 + 64, 0, lds + 12288);
  stage(B, K_DIM, brow0 + 128, 0, lds + 16384);
  stage(B, K_DIM, brow0 + 192, 0, lds + 20480);
  {
    unsigned short* b1 = lds + LDSBUF;
    stage(A, K_DIM, arow0, 1, b1);
    stage(A, K_DIM, arow0 + 64, 1, b1 + 4096);
    stage(B, K_DIM, brow0, 1, b1 + 8192);
    stage(B, K_DIM, brow0 + 64, 1, b1 + 12288);
    stage(B, K_DIM, brow0 + 128, 1, b1 + 16384);
    stage(B, K_DIM, brow0 + 192, 1, b1 + 20480);
  }
  asm volatile("s_waitcnt vmcnt(6)" ::: "memory");
  BAR();

  int cb = 0, sb = 2;
#pragma unroll 1
  for (int t = 0; t < 65; ++t) {
    const unsigned short* bc = lds + cb * LDSBUF;
    unsigned short* sd = lds + sb * LDSBUF;
    int kt2 = t + 2;
    // tile >= 64: lora K-extension (U / LB, row stride 64 elems = 128B = one tile
    // width, kt=0). kt2 = 65,66 are dummy re-stages keeping vmcnt(6) accounting.
    const bool lora = (kt2 >= 64);
    const unsigned short* GA = lora ? U : A;
    const unsigned short* GB = lora ? LB : B;
    const size_t str = lora ? 64 : (size_t)K_DIM;
    const int ktv = lora ? 0 : kt2;

    // ---- phase 1 (ks=0): 3 stage issues + 8 ds_reads + 16 MFMA ----
    stage(GA, str, arow0, ktv, sd);
    stage(GA, str, arow0 + 64, ktv, sd + 4096);
    stage(GB, str, brow0, ktv, sd + 8192);
    COMPUTE_PHASE(0, bc);
    BAR();

    // ---- phase 2 (ks=1) ----
    stage(GB, str, brow0 + 64, ktv, sd + 12288);
    stage(GB, str, brow0 + 128, ktv, sd + 16384);
    stage(GB, str, brow0 + 192, ktv, sd + 20480);
    COMPUTE_PHASE(1, bc);
    asm volatile("s_waitcnt vmcnt(6)" ::: "memory");
    BAR();

    cb = (cb == 2) ? 0 : cb + 1;
    sb = (sb == 2) ? 0 : sb + 1;
  }

  float* Cb = C + (arow0 + (size_t)wr * 64) * N_DIM + brow0 + wc * 64;
#pragma unroll
  for (int mi = 0; mi < 4; ++mi)
#pragma unroll
    for (int ni = 0; ni < 4; ++ni)
#pragma unroll
      for (int r = 0; r < 4; ++r)
        Cb[(size_t)(mi * 16 + lk * 4 + r) * N_DIM + ni * 16 + lr] = acc[mi][ni][r];
}

extern "C" void kernel_launch(void* const* d_in, const int* in_sizes, int n_in,
                              void* d_out, int out_size, void* d_ws, size_t ws_size,
                              hipStream_t stream) {
  const float* input  = (const float*)d_in[0];
  const int* qweight  = (const int*)d_in[1];
  const float* absmax = (const float*)d_in[2];
  const float* lora_A = (const float*)d_in[3];
  const float* lora_B = (const float*)d_in[4];
  float* out = (float*)d_out;

  unsigned short* A16  = (unsigned short*)d_ws;                 // 2048*4096
  unsigned short* B16  = A16 + (size_t)M_DIM * K_DIM;           // 4096*4096
  unsigned short* lB16 = B16 + (size_t)N_DIM * K_DIM;           // 4096*64
  unsigned short* lA16 = lB16 + (size_t)N_DIM * 64;             // 64*4096
  unsigned short* U16  = lA16 + (size_t)64 * K_DIM;             // 2048*64

  // convert input, lora_A, lora_B to bf16
  k_cvt<<<(M_DIM * K_DIM / 4) / 256, 256, 0, stream>>>((const float4*)input,
                                                       (ushort4*)A16, M_DIM * K_DIM / 4);
  k_cvt<<<(64 * K_DIM / 4) / 256, 256, 0, stream>>>((const float4*)lora_A,
                                                    (ushort4*)lA16, 64 * K_DIM / 4);
  k_cvt<<<(N_DIM * 64 / 4) / 256, 256, 0, stream>>>((const float4*)lora_B,
                                                    (ushort4*)lB16, N_DIM * 64 / 4);
  // U = A16 @ lora_A^T  (2048 x 64)
  k_lora_u<<<M_DIM / 128, 256, 0, stream>>>(A16, lA16, U16);
  // W = dequant only (no LoRA)
  k_build_w<<<(N_DIM * K_DIM / 8) / 256, 256, 0, stream>>>(qweight, absmax, B16);
  // C = [A16 | U] @ [B16 | lB16]^T
  k_gemm<<<256, 512, 0, stream>>>(A16, B16, U16, lB16, out);
}

// Round 5
// 107.975 us; speedup vs baseline: 1.6694x; 1.6694x over previous
//
#include <hip/hip_runtime.h>
#include <hip/hip_bf16.h>
#include <stdint.h>

#define M_DIM 2048
#define N_DIM 4096
#define K_DIM 4096

typedef __attribute__((ext_vector_type(8))) __bf16 bf16x8;
typedef __attribute__((ext_vector_type(4))) float f32x4;
typedef __attribute__((ext_vector_type(8))) unsigned short u16x8;

__device__ __constant__ float NF4_TAB[16] = {
    -1.0f, -0.6961928009986877f, -0.5250730514526367f, -0.39491748809814453f,
    -0.28444138169288635f, -0.18477343022823334f, -0.09105003625154495f, 0.0f,
    0.07958029955625534f, 0.16093020141124725f, 0.24611230194568634f,
    0.33791524171829224f, 0.44070982933044434f, 0.5626170039176941f,
    0.7229568362236023f, 1.0f};

// fp32 -> bf16 round-to-nearest-even
__device__ inline unsigned short f2b(float f) {
  union { float f; uint32_t u; } v; v.f = f;
  uint32_t u = v.u;
  return (unsigned short)((u + 0x7fffu + ((u >> 16) & 1u)) >> 16);
}

// ---------------- K1: fp32 -> bf16 (input / lora_A / lora_B) -------------------
__global__ void k_cvt(const float4* __restrict__ in, ushort4* __restrict__ out, int n) {
  int i = blockIdx.x * 256 + threadIdx.x;
  if (i < n) {
    float4 v = in[i];
    ushort4 o;
    o.x = f2b(v.x); o.y = f2b(v.y); o.z = f2b(v.z); o.w = f2b(v.w);
    out[i] = o;
  }
}

// ---------------- K2: pure NF4 dequant -> bf16 W (N x K) -----------------------
__global__ void __launch_bounds__(256) k_build_w(const int* __restrict__ qw,
                                                 const float* __restrict__ am,
                                                 unsigned short* __restrict__ W) {
  __shared__ float tab[16];
  const int t = threadIdx.x;
  if (t < 16) tab[t] = NF4_TAB[t];
  __syncthreads();
  size_t i = (size_t)blockIdx.x * 256 + t;        // group of 8 elems
  int4 q = *(const int4*)(qw + i * 4);
  float amv = am[i >> 3];
  u16x8 o;
  o[0] = f2b(tab[q.x & 15] * amv);  o[1] = f2b(tab[(q.x >> 4) & 15] * amv);
  o[2] = f2b(tab[q.y & 15] * amv);  o[3] = f2b(tab[(q.y >> 4) & 15] * amv);
  o[4] = f2b(tab[q.z & 15] * amv);  o[5] = f2b(tab[(q.z >> 4) & 15] * amv);
  o[6] = f2b(tab[q.w & 15] * amv);  o[7] = f2b(tab[(q.w >> 4) & 15] * amv);
  *(u16x8*)(W + i * 8) = o;
}

// ---------------- K2b: split-K partials of U = A16 @ lora_A16^T ----------------
// grid = 16 m-slabs x 16 K-chunks = 256 blocks (1/CU). Each block: 128 rows x 64
// cols over a 256-wide K-chunk (8 unrolled MFMA steps), f32 partial out.
__global__ void __launch_bounds__(256) k_lora_u(const unsigned short* __restrict__ A16,
                                                const unsigned short* __restrict__ lA16,
                                                float* __restrict__ Up) {
  const int ln = threadIdx.x & 63, w = threadIdx.x >> 6;
  const int lr = ln & 15, lk = ln >> 4;
  const int mslab = blockIdx.x & 15;
  const int kc = blockIdx.x >> 4;          // 16 chunks of 256
  const int m0 = mslab * 128 + w * 32;
  const int k0 = kc * 256;
  f32x4 acc[2][4] = {};
#pragma unroll
  for (int kk = 0; kk < 256; kk += 32) {
    bf16x8 af[2], bv[4];
#pragma unroll
    for (int mi = 0; mi < 2; ++mi)
      af[mi] = *(const bf16x8*)(A16 + (size_t)(m0 + mi * 16 + lr) * K_DIM + k0 + kk + lk * 8);
#pragma unroll
    for (int ni = 0; ni < 4; ++ni)
      bv[ni] = *(const bf16x8*)(lA16 + (size_t)(ni * 16 + lr) * K_DIM + k0 + kk + lk * 8);
#pragma unroll
    for (int mi = 0; mi < 2; ++mi)
#pragma unroll
      for (int ni = 0; ni < 4; ++ni)
        acc[mi][ni] = __builtin_amdgcn_mfma_f32_16x16x32_bf16(af[mi], bv[ni],
                                                              acc[mi][ni], 0, 0, 0);
  }
  float* up = Up + (size_t)kc * (M_DIM * 64);
#pragma unroll
  for (int mi = 0; mi < 2; ++mi)
#pragma unroll
    for (int ni = 0; ni < 4; ++ni)
#pragma unroll
      for (int r = 0; r < 4; ++r)
        up[(size_t)(m0 + mi * 16 + lk * 4 + r) * 64 + ni * 16 + lr] = acc[mi][ni][r];
}

// ---------------- K2c: reduce 16 partials -> bf16 U (deterministic) ------------
__global__ void k_lora_red(const float4* __restrict__ Up, ushort4* __restrict__ U16) {
  int i = blockIdx.x * 256 + threadIdx.x;     // 32768 float4 groups
  float4 s = Up[i];
#pragma unroll
  for (int c = 1; c < 16; ++c) {
    float4 p = Up[(size_t)c * (M_DIM * 64 / 4) + i];
    s.x += p.x; s.y += p.y; s.z += p.z; s.w += p.w;
  }
  ushort4 o; o.x = f2b(s.x); o.y = f2b(s.y); o.z = f2b(s.z); o.w = f2b(s.w);
  U16[i] = o;
}

// ---------------- K3: phased bf16 GEMM + rank-64 K-extension -------------------
// BM=128, BN=256, BK=64. 8 waves 2Mx4N, wave tile 64x64. 3 rotating LDS buffers.
// 65 K-tiles: 0..63 from A16/B16 (stride 4096), tile 64 from U/lB16 (stride 64).
#define LDSBUF 24576  // ushorts per buffer: A 128*64 + B 256*64

#define FENCE() asm volatile("" ::: "memory")
#define BAR() do { FENCE(); __builtin_amdgcn_s_barrier(); FENCE(); } while (0)

#define COMPUTE_PHASE(KS, BC)                                                    \
  do {                                                                           \
    bf16x8 af[4], bv[4];                                                         \
    _Pragma("unroll") for (int mi = 0; mi < 4; ++mi) {                           \
      int row = wr * 64 + mi * 16 + lr;                                          \
      int slot = (((KS) << 2) | lk) ^ (row & 7);                                 \
      af[mi] = *(const bf16x8*)((BC) + row * 64 + slot * 8);                     \
    }                                                                            \
    _Pragma("unroll") for (int ni = 0; ni < 4; ++ni) {                           \
      int row = wc * 64 + ni * 16 + lr;                                          \
      int slot = (((KS) << 2) | lk) ^ (row & 7);                                 \
      bv[ni] = *(const bf16x8*)((BC) + 8192 + row * 64 + slot * 8);              \
    }                                                                            \
    __builtin_amdgcn_s_setprio(1);                                               \
    _Pragma("unroll") for (int mi = 0; mi < 4; ++mi)                             \
    _Pragma("unroll") for (int ni = 0; ni < 4; ++ni)                             \
      acc[mi][ni] = __builtin_amdgcn_mfma_f32_16x16x32_bf16(                     \
          af[mi], bv[ni], acc[mi][ni], 0, 0, 0);                                 \
    __builtin_amdgcn_s_setprio(0);                                               \
  } while (0)

__global__ void __launch_bounds__(512, 2) k_gemm(const unsigned short* __restrict__ A,
                                                 const unsigned short* __restrict__ B,
                                                 const unsigned short* __restrict__ U,
                                                 const unsigned short* __restrict__ LB,
                                                 float* __restrict__ C) {
  __shared__ unsigned short lds[3 * LDSBUF];  // 144 KB
  const int tid = threadIdx.x;
  const int ln = tid & 63;
  const int wid = tid >> 6;  // 0..7
  const int wr = wid >> 2;   // 0..1  (M)
  const int wc = wid & 3;    // 0..3  (N)
  const int lr = ln & 15;
  const int lk = ln >> 4;

  const int sw = (blockIdx.x & 7) * 32 + (blockIdx.x >> 3);
  const int bm = sw & 15;
  const int bn = sw >> 4;
  const size_t arow0 = (size_t)bm * 128;
  const size_t brow0 = (size_t)bn * 256;

  const int srow = (wid << 3) + (ln >> 3);
  const int gs0 = (ln & 7) ^ (srow & 7);
  auto stage = [&](const unsigned short* __restrict__ G, size_t stride, size_t grow0,
                   int kt, unsigned short* dst) {
    const char* g = (const char*)(G + (grow0 + srow) * stride) + kt * 128 + gs0 * 16;
    __builtin_amdgcn_global_load_lds(
        (const __attribute__((address_space(1))) uint32_t*)g,
        (__attribute__((address_space(3))) uint32_t*)(dst + (size_t)(wid << 3) * 64),
        16, 0, 0);
  };

  f32x4 acc[4][4] = {};

  // prologue: K-tiles 0,1 (both regular)
  stage(A, K_DIM, arow0, 0, lds);
  stage(A, K_DIM, arow0 + 64, 0, lds + 4096);
  stage(B, K_DIM, brow0, 0, lds + 8192);
  stage(B, K_DIM, brow0 + 64, 0, lds + 12288);
  stage(B, K_DIM, brow0 + 128, 0, lds + 16384);
  stage(B, K_DIM, brow0 + 192, 0, lds + 20480);
  {
    unsigned short* b1 = lds + LDSBUF;
    stage(A, K_DIM, arow0, 1, b1);
    stage(A, K_DIM, arow0 + 64, 1, b1 + 4096);
    stage(B, K_DIM, brow0, 1, b1 + 8192);
    stage(B, K_DIM, brow0 + 64, 1, b1 + 12288);
    stage(B, K_DIM, brow0 + 128, 1, b1 + 16384);
    stage(B, K_DIM, brow0 + 192, 1, b1 + 20480);
  }
  asm volatile("s_waitcnt vmcnt(6)" ::: "memory");
  BAR();

  int cb = 0, sb = 2;
#pragma unroll 1
  for (int t = 0; t < 65; ++t) {
    const unsigned short* bc = lds + cb * LDSBUF;
    unsigned short* sd = lds + sb * LDSBUF;
    int kt2 = t + 2;
    const bool lora = (kt2 >= 64);
    const unsigned short* GA = lora ? U : A;
    const unsigned short* GB = lora ? LB : B;
    const size_t str = lora ? 64 : (size_t)K_DIM;
    const int ktv = lora ? 0 : kt2;

    // ---- phase 1 (ks=0): 3 stage issues + 8 ds_reads + 16 MFMA ----
    stage(GA, str, arow0, ktv, sd);
    stage(GA, str, arow0 + 64, ktv, sd + 4096);
    stage(GB, str, brow0, ktv, sd + 8192);
    COMPUTE_PHASE(0, bc);
    BAR();

    // ---- phase 2 (ks=1) ----
    stage(GB, str, brow0 + 64, ktv, sd + 12288);
    stage(GB, str, brow0 + 128, ktv, sd + 16384);
    stage(GB, str, brow0 + 192, ktv, sd + 20480);
    COMPUTE_PHASE(1, bc);
    asm volatile("s_waitcnt vmcnt(6)" ::: "memory");
    BAR();

    cb = (cb == 2) ? 0 : cb + 1;
    sb = (sb == 2) ? 0 : sb + 1;
  }

  float* Cb = C + (arow0 + (size_t)wr * 64) * N_DIM + brow0 + wc * 64;
#pragma unroll
  for (int mi = 0; mi < 4; ++mi)
#pragma unroll
    for (int ni = 0; ni < 4; ++ni)
#pragma unroll
      for (int r = 0; r < 4; ++r)
        Cb[(size_t)(mi * 16 + lk * 4 + r) * N_DIM + ni * 16 + lr] = acc[mi][ni][r];
}

extern "C" void kernel_launch(void* const* d_in, const int* in_sizes, int n_in,
                              void* d_out, int out_size, void* d_ws, size_t ws_size,
                              hipStream_t stream) {
  const float* input  = (const float*)d_in[0];
  const int* qweight  = (const int*)d_in[1];
  const float* absmax = (const float*)d_in[2];
  const float* lora_A = (const float*)d_in[3];
  const float* lora_B = (const float*)d_in[4];
  float* out = (float*)d_out;

  unsigned short* A16  = (unsigned short*)d_ws;                 // 2048*4096 bf16
  unsigned short* B16  = A16 + (size_t)M_DIM * K_DIM;           // 4096*4096 bf16
  unsigned short* lB16 = B16 + (size_t)N_DIM * K_DIM;           // 4096*64
  unsigned short* lA16 = lB16 + (size_t)N_DIM * 64;             // 64*4096
  unsigned short* U16  = lA16 + (size_t)64 * K_DIM;             // 2048*64
  // f32 split-K partials alias B16's region (B16 is built AFTER the reduce):
  float* Up = (float*)B16;                                      // 16*2048*64 f32 = 8.4MB

  k_cvt<<<(M_DIM * K_DIM / 4) / 256, 256, 0, stream>>>((const float4*)input,
                                                       (ushort4*)A16, M_DIM * K_DIM / 4);
  k_cvt<<<(64 * K_DIM / 4) / 256, 256, 0, stream>>>((const float4*)lora_A,
                                                    (ushort4*)lA16, 64 * K_DIM / 4);
  k_cvt<<<(N_DIM * 64 / 4) / 256, 256, 0, stream>>>((const float4*)lora_B,
                                                    (ushort4*)lB16, N_DIM * 64 / 4);
  // U partials (split-K), then deterministic reduce -> U16
  k_lora_u<<<256, 256, 0, stream>>>(A16, lA16, Up);
  k_lora_red<<<(M_DIM * 64 / 4) / 256, 256, 0, stream>>>((const float4*)Up,
                                                         (ushort4*)U16);
  // W = dequant only (overwrites the Up alias region)
  k_build_w<<<(N_DIM * K_DIM / 8) / 256, 256, 0, stream>>>(qweight, absmax, B16);
  // C = [A16 | U] @ [B16 | lB16]^T
  k_gemm<<<256, 512, 0, stream>>>(A16, B16, U16, lB16, out);
}

// Round 7
// 104.323 us; speedup vs baseline: 1.7278x; 1.0350x over previous
//
#include <hip/hip_runtime.h>
#include <hip/hip_bf16.h>
#include <stdint.h>

#define M_DIM 2048
#define N_DIM 4096
#define K_DIM 4096

typedef __attribute__((ext_vector_type(8))) __bf16 bf16x8;
typedef __attribute__((ext_vector_type(4))) float f32x4;
typedef __attribute__((ext_vector_type(8))) unsigned short u16x8;

__device__ __constant__ float NF4_TAB[16] = {
    -1.0f, -0.6961928009986877f, -0.5250730514526367f, -0.39491748809814453f,
    -0.28444138169288635f, -0.18477343022823334f, -0.09105003625154495f, 0.0f,
    0.07958029955625534f, 0.16093020141124725f, 0.24611230194568634f,
    0.33791524171829224f, 0.44070982933044434f, 0.5626170039176941f,
    0.7229568362236023f, 1.0f};

// fp32 -> bf16 round-to-nearest-even
__device__ inline unsigned short f2b(float f) {
  union { float f; uint32_t u; } v; v.f = f;
  uint32_t u = v.u;
  return (unsigned short)((u + 0x7fffu + ((u >> 16) & 1u)) >> 16);
}

// ---------------- K1: fused fp32->bf16 for input / lora_A / lora_B -------------
// input: 2097152 f4 -> blocks [0,8192); lora_A: 65536 f4 -> [8192,8448);
// lora_B: 65536 f4 -> [8448,8704)
__global__ void k_cvt3(const float4* __restrict__ in, ushort4* __restrict__ A16,
                       const float4* __restrict__ lA, ushort4* __restrict__ lA16,
                       const float4* __restrict__ lB, ushort4* __restrict__ lB16) {
  int b = blockIdx.x;
  const float4* src;
  ushort4* dst;
  int i;
  if (b < 8192)      { src = in; dst = A16;  i = b * 256 + threadIdx.x; }
  else if (b < 8448) { src = lA; dst = lA16; i = (b - 8192) * 256 + threadIdx.x; }
  else               { src = lB; dst = lB16; i = (b - 8448) * 256 + threadIdx.x; }
  float4 v = src[i];
  ushort4 o;
  o.x = f2b(v.x); o.y = f2b(v.y); o.z = f2b(v.z); o.w = f2b(v.w);
  dst[i] = o;
}

// ---------------- K2: pure NF4 dequant -> bf16 W (N x K) -----------------------
__global__ void __launch_bounds__(256) k_build_w(const int* __restrict__ qw,
                                                 const float* __restrict__ am,
                                                 unsigned short* __restrict__ W) {
  __shared__ float tab[16];
  const int t = threadIdx.x;
  if (t < 16) tab[t] = NF4_TAB[t];
  __syncthreads();
  size_t i = (size_t)blockIdx.x * 256 + t;        // group of 8 elems
  int4 q = *(const int4*)(qw + i * 4);
  float amv = am[i >> 3];
  u16x8 o;
  o[0] = f2b(tab[q.x & 15] * amv);  o[1] = f2b(tab[(q.x >> 4) & 15] * amv);
  o[2] = f2b(tab[q.y & 15] * amv);  o[3] = f2b(tab[(q.y >> 4) & 15] * amv);
  o[4] = f2b(tab[q.z & 15] * amv);  o[5] = f2b(tab[(q.z >> 4) & 15] * amv);
  o[6] = f2b(tab[q.w & 15] * amv);  o[7] = f2b(tab[(q.w >> 4) & 15] * amv);
  *(u16x8*)(W + i * 8) = o;
}

// ---------------- K2b: split-K partials of U = A16 @ lora_A16^T ----------------
__global__ void __launch_bounds__(256) k_lora_u(const unsigned short* __restrict__ A16,
                                                const unsigned short* __restrict__ lA16,
                                                float* __restrict__ Up) {
  const int ln = threadIdx.x & 63, w = threadIdx.x >> 6;
  const int lr = ln & 15, lk = ln >> 4;
  const int mslab = blockIdx.x & 15;
  const int kc = blockIdx.x >> 4;          // 16 chunks of 256
  const int m0 = mslab * 128 + w * 32;
  const int k0 = kc * 256;
  f32x4 acc[2][4] = {};
#pragma unroll
  for (int kk = 0; kk < 256; kk += 32) {
    bf16x8 af[2], bv[4];
#pragma unroll
    for (int mi = 0; mi < 2; ++mi)
      af[mi] = *(const bf16x8*)(A16 + (size_t)(m0 + mi * 16 + lr) * K_DIM + k0 + kk + lk * 8);
#pragma unroll
    for (int ni = 0; ni < 4; ++ni)
      bv[ni] = *(const bf16x8*)(lA16 + (size_t)(ni * 16 + lr) * K_DIM + k0 + kk + lk * 8);
#pragma unroll
    for (int mi = 0; mi < 2; ++mi)
#pragma unroll
      for (int ni = 0; ni < 4; ++ni)
        acc[mi][ni] = __builtin_amdgcn_mfma_f32_16x16x32_bf16(af[mi], bv[ni],
                                                              acc[mi][ni], 0, 0, 0);
  }
  float* up = Up + (size_t)kc * (M_DIM * 64);
#pragma unroll
  for (int mi = 0; mi < 2; ++mi)
#pragma unroll
    for (int ni = 0; ni < 4; ++ni)
#pragma unroll
      for (int r = 0; r < 4; ++r)
        up[(size_t)(m0 + mi * 16 + lk * 4 + r) * 64 + ni * 16 + lr] = acc[mi][ni][r];
}

// ---------------- K2c: reduce 16 partials -> bf16 U (deterministic) ------------
__global__ void k_lora_red(const float4* __restrict__ Up, ushort4* __restrict__ U16) {
  int i = blockIdx.x * 256 + threadIdx.x;     // 32768 float4 groups
  float4 s = Up[i];
#pragma unroll
  for (int c = 1; c < 16; ++c) {
    float4 p = Up[(size_t)c * (M_DIM * 64 / 4) + i];
    s.x += p.x; s.y += p.y; s.z += p.z; s.w += p.w;
  }
  ushort4 o; o.x = f2b(s.x); o.y = f2b(s.y); o.z = f2b(s.z); o.w = f2b(s.w);
  U16[i] = o;
}

// ---------------- K3: phased bf16 GEMM + rank-64 K-extension -------------------
// BM=128, BN=256, BK=64. 8 waves 2Mx4N, wave tile 64x64. 3 rotating LDS buffers.
// 65 K-tiles. m201 phase discipline: per phase {ds_read burst; stage issue;
// s_barrier; lgkmcnt(0)+sched_barrier; setprio(1) 16 MFMA setprio(0); s_barrier}.
// vmcnt(6) once per K-tile (counted, never 0).
#define LDSBUF 24576  // ushorts per buffer: A 128*64 + B 256*64

#define FENCE() asm volatile("" ::: "memory")
#define BAR() do { FENCE(); __builtin_amdgcn_s_barrier(); FENCE(); } while (0)

#define READ_FRAGS(KS, BC, AF, BV)                                               \
  do {                                                                           \
    _Pragma("unroll") for (int mi = 0; mi < 4; ++mi) {                           \
      int row = wr * 64 + mi * 16 + lr;                                          \
      int slot = (((KS) << 2) | lk) ^ (row & 7);                                 \
      AF[mi] = *(const bf16x8*)((BC) + row * 64 + slot * 8);                     \
    }                                                                            \
    _Pragma("unroll") for (int ni = 0; ni < 4; ++ni) {                           \
      int row = wc * 64 + ni * 16 + lr;                                          \
      int slot = (((KS) << 2) | lk) ^ (row & 7);                                 \
      BV[ni] = *(const bf16x8*)((BC) + 8192 + row * 64 + slot * 8);              \
    }                                                                            \
  } while (0)

#define MFMA_CLUSTER(AF, BV)                                                     \
  do {                                                                           \
    __builtin_amdgcn_s_setprio(1);                                               \
    _Pragma("unroll") for (int mi = 0; mi < 4; ++mi)                             \
    _Pragma("unroll") for (int ni = 0; ni < 4; ++ni)                             \
      acc[mi][ni] = __builtin_amdgcn_mfma_f32_16x16x32_bf16(                     \
          AF[mi], BV[ni], acc[mi][ni], 0, 0, 0);                                 \
    __builtin_amdgcn_s_setprio(0);                                               \
  } while (0)

__global__ void __launch_bounds__(512, 2) k_gemm(const unsigned short* __restrict__ A,
                                                 const unsigned short* __restrict__ B,
                                                 const unsigned short* __restrict__ U,
                                                 const unsigned short* __restrict__ LB,
                                                 float* __restrict__ C) {
  __shared__ unsigned short lds[3 * LDSBUF];  // 144 KB
  const int tid = threadIdx.x;
  const int ln = tid & 63;
  const int wid = tid >> 6;  // 0..7
  const int wr = wid >> 2;   // 0..1  (M)
  const int wc = wid & 3;    // 0..3  (N)
  const int lr = ln & 15;
  const int lk = ln >> 4;

  const int sw = (blockIdx.x & 7) * 32 + (blockIdx.x >> 3);
  const int bm = sw & 15;
  const int bn = sw >> 4;
  const size_t arow0 = (size_t)bm * 128;
  const size_t brow0 = (size_t)bn * 256;

  const int srow = (wid << 3) + (ln >> 3);
  const int gs0 = (ln & 7) ^ (srow & 7);
  auto stage = [&](const unsigned short* __restrict__ G, size_t stride, size_t grow0,
                   int kt, unsigned short* dst) {
    const char* g = (const char*)(G + (grow0 + srow) * stride) + kt * 128 + gs0 * 16;
    __builtin_amdgcn_global_load_lds(
        (const __attribute__((address_space(1))) uint32_t*)g,
        (__attribute__((address_space(3))) uint32_t*)(dst + (size_t)(wid << 3) * 64),
        16, 0, 0);
  };

  f32x4 acc[4][4] = {};

  // prologue: K-tiles 0,1 (both regular)
  stage(A, K_DIM, arow0, 0, lds);
  stage(A, K_DIM, arow0 + 64, 0, lds + 4096);
  stage(B, K_DIM, brow0, 0, lds + 8192);
  stage(B, K_DIM, brow0 + 64, 0, lds + 12288);
  stage(B, K_DIM, brow0 + 128, 0, lds + 16384);
  stage(B, K_DIM, brow0 + 192, 0, lds + 20480);
  {
    unsigned short* b1 = lds + LDSBUF;
    stage(A, K_DIM, arow0, 1, b1);
    stage(A, K_DIM, arow0 + 64, 1, b1 + 4096);
    stage(B, K_DIM, brow0, 1, b1 + 8192);
    stage(B, K_DIM, brow0 + 64, 1, b1 + 12288);
    stage(B, K_DIM, brow0 + 128, 1, b1 + 16384);
    stage(B, K_DIM, brow0 + 192, 1, b1 + 20480);
  }
  asm volatile("s_waitcnt vmcnt(6)" ::: "memory");
  BAR();

  int cb = 0, sb = 2;
#pragma unroll 1
  for (int t = 0; t < 65; ++t) {
    const unsigned short* bc = lds + cb * LDSBUF;
    unsigned short* sd = lds + sb * LDSBUF;
    int kt2 = t + 2;
    const bool lora = (kt2 >= 64);
    const unsigned short* GA = lora ? U : A;
    const unsigned short* GB = lora ? LB : B;
    const size_t str = lora ? 64 : (size_t)K_DIM;
    const int ktv = lora ? 0 : kt2;

    // ---- phase 1 (ks=0) ----
    {
      bf16x8 af[4], bv[4];
      READ_FRAGS(0, bc, af, bv);
      stage(GA, str, arow0, ktv, sd);
      stage(GA, str, arow0 + 64, ktv, sd + 4096);
      stage(GB, str, brow0, ktv, sd + 8192);
      BAR();  // all waves' LDS-read bursts issued before any MFMA starts
      asm volatile("s_waitcnt lgkmcnt(0)" ::: "memory");
      __builtin_amdgcn_sched_barrier(0);
      MFMA_CLUSTER(af, bv);
      BAR();
    }

    // ---- phase 2 (ks=1) ----
    {
      bf16x8 af[4], bv[4];
      READ_FRAGS(1, bc, af, bv);
      stage(GB, str, brow0 + 64, ktv, sd + 12288);
      stage(GB, str, brow0 + 128, ktv, sd + 16384);
      stage(GB, str, brow0 + 192, ktv, sd + 20480);
      // counted wait: this iter's 6 loads may stay in flight; tile t+1 must be done
      asm volatile("s_waitcnt vmcnt(6)" ::: "memory");
      BAR();
      asm volatile("s_waitcnt lgkmcnt(0)" ::: "memory");
      __builtin_amdgcn_sched_barrier(0);
      MFMA_CLUSTER(af, bv);
      BAR();
    }

    cb = (cb == 2) ? 0 : cb + 1;
    sb = (sb == 2) ? 0 : sb + 1;
  }

  float* Cb = C + (arow0 + (size_t)wr * 64) * N_DIM + brow0 + wc * 64;
#pragma unroll
  for (int mi = 0; mi < 4; ++mi)
#pragma unroll
    for (int ni = 0; ni < 4; ++ni)
#pragma unroll
      for (int r = 0; r < 4; ++r)
        Cb[(size_t)(mi * 16 + lk * 4 + r) * N_DIM + ni * 16 + lr] = acc[mi][ni][r];
}

extern "C" void kernel_launch(void* const* d_in, const int* in_sizes, int n_in,
                              void* d_out, int out_size, void* d_ws, size_t ws_size,
                              hipStream_t stream) {
  const float* input  = (const float*)d_in[0];
  const int* qweight  = (const int*)d_in[1];
  const float* absmax = (const float*)d_in[2];
  const float* lora_A = (const float*)d_in[3];
  const float* lora_B = (const float*)d_in[4];
  float* out = (float*)d_out;

  unsigned short* A16  = (unsigned short*)d_ws;                 // 2048*4096 bf16
  unsigned short* B16  = A16 + (size_t)M_DIM * K_DIM;           // 4096*4096 bf16
  unsigned short* lB16 = B16 + (size_t)N_DIM * K_DIM;           // 4096*64
  unsigned short* lA16 = lB16 + (size_t)N_DIM * 64;             // 64*4096
  unsigned short* U16  = lA16 + (size_t)64 * K_DIM;             // 2048*64
  // f32 split-K partials alias B16's region (B16 is built AFTER the reduce):
  float* Up = (float*)B16;                                      // 16*2048*64 f32

  // fused cvt: input (8192 blocks) + lora_A (256) + lora_B (256)
  k_cvt3<<<8704, 256, 0, stream>>>((const float4*)input, (ushort4*)A16,
                                   (const float4*)lora_A, (ushort4*)lA16,
                                   (const float4*)lora_B, (ushort4*)lB16);
  // U partials (split-K), then deterministic reduce -> U16
  k_lora_u<<<256, 256, 0, stream>>>(A16, lA16, Up);
  k_lora_red<<<(M_DIM * 64 / 4) / 256, 256, 0, stream>>>((const float4*)Up,
                                                         (ushort4*)U16);
  // W = dequant only (overwrites the Up alias region)
  k_build_w<<<(N_DIM * K_DIM / 8) / 256, 256, 0, stream>>>(qweight, absmax, B16);
  // C = [A16 | U] @ [B16 | lB16]^T
  k_gemm<<<256, 512, 0, stream>>>(A16, B16, U16, lB16, out);
}

// Round 8
// 103.672 us; speedup vs baseline: 1.7386x; 1.0063x over previous
//
#include <hip/hip_runtime.h>
#include <hip/hip_bf16.h>
#include <stdint.h>

#define M_DIM 2048
#define N_DIM 4096
#define K_DIM 4096

typedef __attribute__((ext_vector_type(8))) __bf16 bf16x8;
typedef __attribute__((ext_vector_type(4))) float f32x4;
typedef __attribute__((ext_vector_type(8))) unsigned short u16x8;

__device__ __constant__ float NF4_TAB[16] = {
    -1.0f, -0.6961928009986877f, -0.5250730514526367f, -0.39491748809814453f,
    -0.28444138169288635f, -0.18477343022823334f, -0.09105003625154495f, 0.0f,
    0.07958029955625534f, 0.16093020141124725f, 0.24611230194568634f,
    0.33791524171829224f, 0.44070982933044434f, 0.5626170039176941f,
    0.7229568362236023f, 1.0f};

// fp32 -> bf16 round-to-nearest-even
__device__ inline unsigned short f2b(float f) {
  union { float f; uint32_t u; } v; v.f = f;
  uint32_t u = v.u;
  return (unsigned short)((u + 0x7fffu + ((u >> 16) & 1u)) >> 16);
}

// ---------------- K1: fused fp32->bf16 for input / lora_A / lora_B -------------
// input: 2097152 f4 -> blocks [0,8192); lora_A: [8192,8448); lora_B: [8448,8704)
__global__ void k_cvt3(const float4* __restrict__ in, ushort4* __restrict__ A16,
                       const float4* __restrict__ lA, ushort4* __restrict__ lA16,
                       const float4* __restrict__ lB, ushort4* __restrict__ lB16) {
  int b = blockIdx.x;
  const float4* src;
  ushort4* dst;
  int i;
  if (b < 8192)      { src = in; dst = A16;  i = b * 256 + threadIdx.x; }
  else if (b < 8448) { src = lA; dst = lA16; i = (b - 8192) * 256 + threadIdx.x; }
  else               { src = lB; dst = lB16; i = (b - 8448) * 256 + threadIdx.x; }
  float4 v = src[i];
  ushort4 o;
  o.x = f2b(v.x); o.y = f2b(v.y); o.z = f2b(v.z); o.w = f2b(v.w);
  dst[i] = o;
}

// ---------------- K2: pure NF4 dequant -> bf16 W (N x K) -----------------------
__global__ void __launch_bounds__(256) k_build_w(const int* __restrict__ qw,
                                                 const float* __restrict__ am,
                                                 unsigned short* __restrict__ W) {
  __shared__ float tab[16];
  const int t = threadIdx.x;
  if (t < 16) tab[t] = NF4_TAB[t];
  __syncthreads();
  size_t i = (size_t)blockIdx.x * 256 + t;        // group of 8 elems
  int4 q = *(const int4*)(qw + i * 4);
  float amv = am[i >> 3];
  u16x8 o;
  o[0] = f2b(tab[q.x & 15] * amv);  o[1] = f2b(tab[(q.x >> 4) & 15] * amv);
  o[2] = f2b(tab[q.y & 15] * amv);  o[3] = f2b(tab[(q.y >> 4) & 15] * amv);
  o[4] = f2b(tab[q.z & 15] * amv);  o[5] = f2b(tab[(q.z >> 4) & 15] * amv);
  o[6] = f2b(tab[q.w & 15] * amv);  o[7] = f2b(tab[(q.w >> 4) & 15] * amv);
  *(u16x8*)(W + i * 8) = o;
}

// ---------------- K2b: split-K partials of U = A16 @ lora_A16^T ----------------
__global__ void __launch_bounds__(256) k_lora_u(const unsigned short* __restrict__ A16,
                                                const unsigned short* __restrict__ lA16,
                                                float* __restrict__ Up) {
  const int ln = threadIdx.x & 63, w = threadIdx.x >> 6;
  const int lr = ln & 15, lk = ln >> 4;
  const int mslab = blockIdx.x & 15;
  const int kc = blockIdx.x >> 4;          // 16 chunks of 256
  const int m0 = mslab * 128 + w * 32;
  const int k0 = kc * 256;
  f32x4 acc[2][4] = {};
#pragma unroll
  for (int kk = 0; kk < 256; kk += 32) {
    bf16x8 af[2], bv[4];
#pragma unroll
    for (int mi = 0; mi < 2; ++mi)
      af[mi] = *(const bf16x8*)(A16 + (size_t)(m0 + mi * 16 + lr) * K_DIM + k0 + kk + lk * 8);
#pragma unroll
    for (int ni = 0; ni < 4; ++ni)
      bv[ni] = *(const bf16x8*)(lA16 + (size_t)(ni * 16 + lr) * K_DIM + k0 + kk + lk * 8);
#pragma unroll
    for (int mi = 0; mi < 2; ++mi)
#pragma unroll
      for (int ni = 0; ni < 4; ++ni)
        acc[mi][ni] = __builtin_amdgcn_mfma_f32_16x16x32_bf16(af[mi], bv[ni],
                                                              acc[mi][ni], 0, 0, 0);
  }
  float* up = Up + (size_t)kc * (M_DIM * 64);
#pragma unroll
  for (int mi = 0; mi < 2; ++mi)
#pragma unroll
    for (int ni = 0; ni < 4; ++ni)
#pragma unroll
      for (int r = 0; r < 4; ++r)
        up[(size_t)(m0 + mi * 16 + lk * 4 + r) * 64 + ni * 16 + lr] = acc[mi][ni][r];
}

// ---------------- K2c: reduce 16 partials -> bf16 U (deterministic) ------------
__global__ void k_lora_red(const float4* __restrict__ Up, ushort4* __restrict__ U16) {
  int i = blockIdx.x * 256 + threadIdx.x;     // 32768 float4 groups
  float4 s = Up[i];
#pragma unroll
  for (int c = 1; c < 16; ++c) {
    float4 p = Up[(size_t)c * (M_DIM * 64 / 4) + i];
    s.x += p.x; s.y += p.y; s.z += p.z; s.w += p.w;
  }
  ushort4 o; o.x = f2b(s.x); o.y = f2b(s.y); o.z = f2b(s.z); o.w = f2b(s.w);
  U16[i] = o;
}

// ---------------- K3: bf16 GEMM + rank-64 K-extension --------------------------
// BM=128, BN=256, BK=64. 8 waves 2Mx4N, wave tile 64x64. 3 rotating LDS buffers.
// 65 K-tiles. ONE barrier + ONE vmcnt(6) per K-tile: {6 stage issues; 16
// ds_reads; 32 MFMA; vmcnt(6); barrier}. Waves skew freely within the span so
// one wave's ds_reads overlap its SIMD-partner's MFMAs (cross-wave pipe overlap).
// Hazard proof: reads of buffer b at tile t drain (compiler lgkmcnt before MFMA
// use) before the wave reaches barrier t; stages into b recur at t+1 after that
// barrier. Loads issued at t complete before use at t+2 (vmcnt(6) at t+1).
#define LDSBUF 24576  // ushorts per buffer: A 128*64 + B 256*64

#define FENCE() asm volatile("" ::: "memory")
#define BAR() do { FENCE(); __builtin_amdgcn_s_barrier(); FENCE(); } while (0)

__global__ void __launch_bounds__(512, 2) k_gemm(const unsigned short* __restrict__ A,
                                                 const unsigned short* __restrict__ B,
                                                 const unsigned short* __restrict__ U,
                                                 const unsigned short* __restrict__ LB,
                                                 float* __restrict__ C) {
  __shared__ unsigned short lds[3 * LDSBUF];  // 144 KB
  const int tid = threadIdx.x;
  const int ln = tid & 63;
  const int wid = tid >> 6;  // 0..7
  const int wr = wid >> 2;   // 0..1  (M)
  const int wc = wid & 3;    // 0..3  (N)
  const int lr = ln & 15;
  const int lk = ln >> 4;

  const int sw = (blockIdx.x & 7) * 32 + (blockIdx.x >> 3);
  const int bm = sw & 15;
  const int bn = sw >> 4;
  const size_t arow0 = (size_t)bm * 128;
  const size_t brow0 = (size_t)bn * 256;

  const int srow = (wid << 3) + (ln >> 3);
  const int gs0 = (ln & 7) ^ (srow & 7);
  auto stage = [&](const unsigned short* __restrict__ G, size_t stride, size_t grow0,
                   int kt, unsigned short* dst) {
    const char* g = (const char*)(G + (grow0 + srow) * stride) + kt * 128 + gs0 * 16;
    __builtin_amdgcn_global_load_lds(
        (const __attribute__((address_space(1))) uint32_t*)g,
        (__attribute__((address_space(3))) uint32_t*)(dst + (size_t)(wid << 3) * 64),
        16, 0, 0);
  };

  f32x4 acc[4][4] = {};

  // prologue: K-tiles 0,1 (both regular)
  stage(A, K_DIM, arow0, 0, lds);
  stage(A, K_DIM, arow0 + 64, 0, lds + 4096);
  stage(B, K_DIM, brow0, 0, lds + 8192);
  stage(B, K_DIM, brow0 + 64, 0, lds + 12288);
  stage(B, K_DIM, brow0 + 128, 0, lds + 16384);
  stage(B, K_DIM, brow0 + 192, 0, lds + 20480);
  {
    unsigned short* b1 = lds + LDSBUF;
    stage(A, K_DIM, arow0, 1, b1);
    stage(A, K_DIM, arow0 + 64, 1, b1 + 4096);
    stage(B, K_DIM, brow0, 1, b1 + 8192);
    stage(B, K_DIM, brow0 + 64, 1, b1 + 12288);
    stage(B, K_DIM, brow0 + 128, 1, b1 + 16384);
    stage(B, K_DIM, brow0 + 192, 1, b1 + 20480);
  }
  asm volatile("s_waitcnt vmcnt(6)" ::: "memory");  // K-tile 0 landed; K1 in flight
  BAR();

  int cb = 0, sb = 2;
#pragma unroll 1
  for (int t = 0; t < 65; ++t) {
    const unsigned short* bc = lds + cb * LDSBUF;
    unsigned short* sd = lds + sb * LDSBUF;
    int kt2 = t + 2;
    const bool lora = (kt2 >= 64);
    const unsigned short* GA = lora ? U : A;
    const unsigned short* GB = lora ? LB : B;
    const size_t str = lora ? 64 : (size_t)K_DIM;
    const int ktv = lora ? 0 : kt2;

    // 6 stage issues for K-tile t+2 (HBM latency hides under this whole tile)
    stage(GA, str, arow0, ktv, sd);
    stage(GA, str, arow0 + 64, ktv, sd + 4096);
    stage(GB, str, brow0, ktv, sd + 8192);
    stage(GB, str, brow0 + 64, ktv, sd + 12288);
    stage(GB, str, brow0 + 128, ktv, sd + 16384);
    stage(GB, str, brow0 + 192, ktv, sd + 20480);

    // 16 ds_read_b128 (both K-halves), compiler interleaves lgkmcnt with MFMA
    bf16x8 af[4][2], bv[4][2];
#pragma unroll
    for (int mi = 0; mi < 4; ++mi) {
      int row = wr * 64 + mi * 16 + lr;
      int rb = row * 64, x = row & 7;
#pragma unroll
      for (int ks = 0; ks < 2; ++ks) {
        int slot = ((ks << 2) | lk) ^ x;
        af[mi][ks] = *(const bf16x8*)(bc + rb + slot * 8);
      }
    }
#pragma unroll
    for (int ni = 0; ni < 4; ++ni) {
      int row = wc * 64 + ni * 16 + lr;
      int rb = 8192 + row * 64, x = row & 7;
#pragma unroll
      for (int ks = 0; ks < 2; ++ks) {
        int slot = ((ks << 2) | lk) ^ x;
        bv[ni][ks] = *(const bf16x8*)(bc + rb + slot * 8);
      }
    }

    __builtin_amdgcn_s_setprio(1);
#pragma unroll
    for (int ks = 0; ks < 2; ++ks)
#pragma unroll
      for (int mi = 0; mi < 4; ++mi)
#pragma unroll
        for (int ni = 0; ni < 4; ++ni)
          acc[mi][ni] = __builtin_amdgcn_mfma_f32_16x16x32_bf16(
              af[mi][ks], bv[ni][ks], acc[mi][ni], 0, 0, 0);
    __builtin_amdgcn_s_setprio(0);

    // counted wait: this tile's 6 loads stay in flight; tile t+1's are complete
    asm volatile("s_waitcnt vmcnt(6)" ::: "memory");
    BAR();

    cb = (cb == 2) ? 0 : cb + 1;
    sb = (sb == 2) ? 0 : sb + 1;
  }

  // epilogue: C/D layout col = lane&15, row = (lane>>4)*4 + reg
  float* Cb = C + (arow0 + (size_t)wr * 64) * N_DIM + brow0 + wc * 64;
#pragma unroll
  for (int mi = 0; mi < 4; ++mi)
#pragma unroll
    for (int ni = 0; ni < 4; ++ni)
#pragma unroll
      for (int r = 0; r < 4; ++r)
        Cb[(size_t)(mi * 16 + lk * 4 + r) * N_DIM + ni * 16 + lr] = acc[mi][ni][r];
}

extern "C" void kernel_launch(void* const* d_in, const int* in_sizes, int n_in,
                              void* d_out, int out_size, void* d_ws, size_t ws_size,
                              hipStream_t stream) {
  const float* input  = (const float*)d_in[0];
  const int* qweight  = (const int*)d_in[1];
  const float* absmax = (const float*)d_in[2];
  const float* lora_A = (const float*)d_in[3];
  const float* lora_B = (const float*)d_in[4];
  float* out = (float*)d_out;

  unsigned short* A16  = (unsigned short*)d_ws;                 // 2048*4096 bf16
  unsigned short* B16  = A16 + (size_t)M_DIM * K_DIM;           // 4096*4096 bf16
  unsigned short* lB16 = B16 + (size_t)N_DIM * K_DIM;           // 4096*64
  unsigned short* lA16 = lB16 + (size_t)N_DIM * 64;             // 64*4096
  unsigned short* U16  = lA16 + (size_t)64 * K_DIM;             // 2048*64
  // f32 split-K partials alias B16's region (B16 is built AFTER the reduce):
  float* Up = (float*)B16;                                      // 16*2048*64 f32

  // fused cvt: input (8192 blocks) + lora_A (256) + lora_B (256)
  k_cvt3<<<8704, 256, 0, stream>>>((const float4*)input, (ushort4*)A16,
                                   (const float4*)lora_A, (ushort4*)lA16,
                                   (const float4*)lora_B, (ushort4*)lB16);
  // U partials (split-K), then deterministic reduce -> U16
  k_lora_u<<<256, 256, 0, stream>>>(A16, lA16, Up);
  k_lora_red<<<(M_DIM * 64 / 4) / 256, 256, 0, stream>>>((const float4*)Up,
                                                         (ushort4*)U16);
  // W = dequant only (overwrites the Up alias region)
  k_build_w<<<(N_DIM * K_DIM / 8) / 256, 256, 0, stream>>>(qweight, absmax, B16);
  // C = [A16 | U] @ [B16 | lB16]^T
  k_gemm<<<256, 512, 0, stream>>>(A16, B16, U16, lB16, out);
}

// Round 11
// 101.783 us; speedup vs baseline: 1.7709x; 1.0186x over previous
//
#include <hip/hip_runtime.h>
#include <hip/hip_bf16.h>
#include <stdint.h>

#define M_DIM 2048
#define N_DIM 4096
#define K_DIM 4096

typedef __attribute__((ext_vector_type(8))) __bf16 bf16x8;
typedef __attribute__((ext_vector_type(4))) float f32x4;
typedef __attribute__((ext_vector_type(8))) unsigned short u16x8;

__device__ __constant__ float NF4_TAB[16] = {
    -1.0f, -0.6961928009986877f, -0.5250730514526367f, -0.39491748809814453f,
    -0.28444138169288635f, -0.18477343022823334f, -0.09105003625154495f, 0.0f,
    0.07958029955625534f, 0.16093020141124725f, 0.24611230194568634f,
    0.33791524171829224f, 0.44070982933044434f, 0.5626170039176941f,
    0.7229568362236023f, 1.0f};

// fp32 -> bf16 round-to-nearest-even
__device__ inline unsigned short f2b(float f) {
  union { float f; uint32_t u; } v; v.f = f;
  uint32_t u = v.u;
  return (unsigned short)((u + 0x7fffu + ((u >> 16) & 1u)) >> 16);
}

// ---------------- K1: fused prep -------------------------------------------------
// blocks [0,8192): input cvt; [8192,8448): lora_A cvt; [8448,8704): lora_B cvt;
// [8704,16896): NF4 dequant -> B16 (independent of the cvt segments).
__global__ void __launch_bounds__(256) k_prep(
    const float4* __restrict__ in, ushort4* __restrict__ A16,
    const float4* __restrict__ lA, ushort4* __restrict__ lA16,
    const float4* __restrict__ lB, ushort4* __restrict__ lB16,
    const int* __restrict__ qw, const float* __restrict__ am,
    unsigned short* __restrict__ W) {
  const int b = blockIdx.x;
  const int t = threadIdx.x;
  if (b < 8704) {
    const float4* src;
    ushort4* dst;
    int i;
    if (b < 8192)      { src = in; dst = A16;  i = b * 256 + t; }
    else if (b < 8448) { src = lA; dst = lA16; i = (b - 8192) * 256 + t; }
    else               { src = lB; dst = lB16; i = (b - 8448) * 256 + t; }
    float4 v = src[i];
    ushort4 o;
    o.x = f2b(v.x); o.y = f2b(v.y); o.z = f2b(v.z); o.w = f2b(v.w);
    dst[i] = o;
  } else {
    __shared__ float tab[16];
    if (t < 16) tab[t] = NF4_TAB[t];
    __syncthreads();
    size_t i = (size_t)(b - 8704) * 256 + t;        // group of 8 elems
    int4 q = *(const int4*)(qw + i * 4);
    float amv = am[i >> 3];
    u16x8 o;
    o[0] = f2b(tab[q.x & 15] * amv);  o[1] = f2b(tab[(q.x >> 4) & 15] * amv);
    o[2] = f2b(tab[q.y & 15] * amv);  o[3] = f2b(tab[(q.y >> 4) & 15] * amv);
    o[4] = f2b(tab[q.z & 15] * amv);  o[5] = f2b(tab[(q.z >> 4) & 15] * amv);
    o[6] = f2b(tab[q.w & 15] * amv);  o[7] = f2b(tab[(q.w >> 4) & 15] * amv);
    *(u16x8*)(W + i * 8) = o;
  }
}

// ---------------- K2b: split-K partials of U = A16 @ lora_A16^T ----------------
__global__ void __launch_bounds__(256) k_lora_u(const unsigned short* __restrict__ A16,
                                                const unsigned short* __restrict__ lA16,
                                                float* __restrict__ Up) {
  const int ln = threadIdx.x & 63, w = threadIdx.x >> 6;
  const int lr = ln & 15, lk = ln >> 4;
  const int mslab = blockIdx.x & 15;
  const int kc = blockIdx.x >> 4;          // 16 chunks of 256
  const int m0 = mslab * 128 + w * 32;
  const int k0 = kc * 256;
  f32x4 acc[2][4] = {};
#pragma unroll
  for (int kk = 0; kk < 256; kk += 32) {
    bf16x8 af[2], bv[4];
#pragma unroll
    for (int mi = 0; mi < 2; ++mi)
      af[mi] = *(const bf16x8*)(A16 + (size_t)(m0 + mi * 16 + lr) * K_DIM + k0 + kk + lk * 8);
#pragma unroll
    for (int ni = 0; ni < 4; ++ni)
      bv[ni] = *(const bf16x8*)(lA16 + (size_t)(ni * 16 + lr) * K_DIM + k0 + kk + lk * 8);
#pragma unroll
    for (int mi = 0; mi < 2; ++mi)
#pragma unroll
      for (int ni = 0; ni < 4; ++ni)
        acc[mi][ni] = __builtin_amdgcn_mfma_f32_16x16x32_bf16(af[mi], bv[ni],
                                                              acc[mi][ni], 0, 0, 0);
  }
  float* up = Up + (size_t)kc * (M_DIM * 64);
#pragma unroll
  for (int mi = 0; mi < 2; ++mi)
#pragma unroll
    for (int ni = 0; ni < 4; ++ni)
#pragma unroll
      for (int r = 0; r < 4; ++r)
        up[(size_t)(m0 + mi * 16 + lk * 4 + r) * 64 + ni * 16 + lr] = acc[mi][ni][r];
}

// ---------------- K2c: reduce 16 partials -> bf16 U (deterministic) ------------
__global__ void k_lora_red(const float4* __restrict__ Up, ushort4* __restrict__ U16) {
  int i = blockIdx.x * 256 + threadIdx.x;     // 32768 float4 groups
  float4 s = Up[i];
#pragma unroll
  for (int c = 1; c < 16; ++c) {
    float4 p = Up[(size_t)c * (M_DIM * 64 / 4) + i];
    s.x += p.x; s.y += p.y; s.z += p.z; s.w += p.w;
  }
  ushort4 o; o.x = f2b(s.x); o.y = f2b(s.y); o.z = f2b(s.z); o.w = f2b(s.w);
  U16[i] = o;
}

// ---------------- K3: bf16 GEMM + rank-64 K-extension (exact R8, known-good) ---
// BM=128, BN=256, BK=64. 8 waves 2Mx4N, wave tile 64x64. 3 rotating LDS buffers.
// 65 K-tiles. ONE barrier + ONE vmcnt(6) per K-tile.
#define LDSBUF 24576  // ushorts per buffer: A 128*64 + B 256*64

#define FENCE() asm volatile("" ::: "memory")
#define BAR() do { FENCE(); __builtin_amdgcn_s_barrier(); FENCE(); } while (0)

__global__ void __launch_bounds__(512, 2) k_gemm(const unsigned short* __restrict__ A,
                                                 const unsigned short* __restrict__ B,
                                                 const unsigned short* __restrict__ U,
                                                 const unsigned short* __restrict__ LB,
                                                 float* __restrict__ C) {
  __shared__ unsigned short lds[3 * LDSBUF];  // 144 KB
  const int tid = threadIdx.x;
  const int ln = tid & 63;
  const int wid = tid >> 6;  // 0..7
  const int wr = wid >> 2;   // 0..1  (M)
  const int wc = wid & 3;    // 0..3  (N)
  const int lr = ln & 15;
  const int lk = ln >> 4;

  const int sw = (blockIdx.x & 7) * 32 + (blockIdx.x >> 3);
  const int bm = sw & 15;
  const int bn = sw >> 4;
  const size_t arow0 = (size_t)bm * 128;
  const size_t brow0 = (size_t)bn * 256;

  const int srow = (wid << 3) + (ln >> 3);
  const int gs0 = (ln & 7) ^ (srow & 7);
  auto stage = [&](const unsigned short* __restrict__ G, size_t stride, size_t grow0,
                   int kt, unsigned short* dst) {
    const char* g = (const char*)(G + (grow0 + srow) * stride) + kt * 128 + gs0 * 16;
    __builtin_amdgcn_global_load_lds(
        (const __attribute__((address_space(1))) uint32_t*)g,
        (__attribute__((address_space(3))) uint32_t*)(dst + (size_t)(wid << 3) * 64),
        16, 0, 0);
  };

  f32x4 acc[4][4] = {};

  // prologue: K-tiles 0,1 (both regular)
  stage(A, K_DIM, arow0, 0, lds);
  stage(A, K_DIM, arow0 + 64, 0, lds + 4096);
  stage(B, K_DIM, brow0, 0, lds + 8192);
  stage(B, K_DIM, brow0 + 64, 0, lds + 12288);
  stage(B, K_DIM, brow0 + 128, 0, lds + 16384);
  stage(B, K_DIM, brow0 + 192, 0, lds + 20480);
  {
    unsigned short* b1 = lds + LDSBUF;
    stage(A, K_DIM, arow0, 1, b1);
    stage(A, K_DIM, arow0 + 64, 1, b1 + 4096);
    stage(B, K_DIM, brow0, 1, b1 + 8192);
    stage(B, K_DIM, brow0 + 64, 1, b1 + 12288);
    stage(B, K_DIM, brow0 + 128, 1, b1 + 16384);
    stage(B, K_DIM, brow0 + 192, 1, b1 + 20480);
  }
  asm volatile("s_waitcnt vmcnt(6)" ::: "memory");  // K-tile 0 landed; K1 in flight
  BAR();

  int cb = 0, sb = 2;
#pragma unroll 1
  for (int t = 0; t < 65; ++t) {
    const unsigned short* bc = lds + cb * LDSBUF;
    unsigned short* sd = lds + sb * LDSBUF;
    int kt2 = t + 2;
    const bool lora = (kt2 >= 64);
    const unsigned short* GA = lora ? U : A;
    const unsigned short* GB = lora ? LB : B;
    const size_t str = lora ? 64 : (size_t)K_DIM;
    const int ktv = lora ? 0 : kt2;

    // 6 stage issues for K-tile t+2 (HBM latency hides under this whole tile)
    stage(GA, str, arow0, ktv, sd);
    stage(GA, str, arow0 + 64, ktv, sd + 4096);
    stage(GB, str, brow0, ktv, sd + 8192);
    stage(GB, str, brow0 + 64, ktv, sd + 12288);
    stage(GB, str, brow0 + 128, ktv, sd + 16384);
    stage(GB, str, brow0 + 192, ktv, sd + 20480);

    // 16 ds_read_b128 (both K-halves), compiler interleaves lgkmcnt with MFMA
    bf16x8 af[4][2], bv[4][2];
#pragma unroll
    for (int mi = 0; mi < 4; ++mi) {
      int row = wr * 64 + mi * 16 + lr;
      int rb = row * 64, x = row & 7;
#pragma unroll
      for (int ks = 0; ks < 2; ++ks) {
        int slot = ((ks << 2) | lk) ^ x;
        af[mi][ks] = *(const bf16x8*)(bc + rb + slot * 8);
      }
    }
#pragma unroll
    for (int ni = 0; ni < 4; ++ni) {
      int row = wc * 64 + ni * 16 + lr;
      int rb = 8192 + row * 64, x = row & 7;
#pragma unroll
      for (int ks = 0; ks < 2; ++ks) {
        int slot = ((ks << 2) | lk) ^ x;
        bv[ni][ks] = *(const bf16x8*)(bc + rb + slot * 8);
      }
    }

    __builtin_amdgcn_s_setprio(1);
#pragma unroll
    for (int ks = 0; ks < 2; ++ks)
#pragma unroll
      for (int mi = 0; mi < 4; ++mi)
#pragma unroll
        for (int ni = 0; ni < 4; ++ni)
          acc[mi][ni] = __builtin_amdgcn_mfma_f32_16x16x32_bf16(
              af[mi][ks], bv[ni][ks], acc[mi][ni], 0, 0, 0);
    __builtin_amdgcn_s_setprio(0);

    // counted wait: this tile's 6 loads stay in flight; tile t+1's are complete
    asm volatile("s_waitcnt vmcnt(6)" ::: "memory");
    BAR();

    cb = (cb == 2) ? 0 : cb + 1;
    sb = (sb == 2) ? 0 : sb + 1;
  }

  // epilogue: C/D layout col = lane&15, row = (lane>>4)*4 + reg
  float* Cb = C + (arow0 + (size_t)wr * 64) * N_DIM + brow0 + wc * 64;
#pragma unroll
  for (int mi = 0; mi < 4; ++mi)
#pragma unroll
    for (int ni = 0; ni < 4; ++ni)
#pragma unroll
      for (int r = 0; r < 4; ++r)
        Cb[(size_t)(mi * 16 + lk * 4 + r) * N_DIM + ni * 16 + lr] = acc[mi][ni][r];
}

extern "C" void kernel_launch(void* const* d_in, const int* in_sizes, int n_in,
                              void* d_out, int out_size, void* d_ws, size_t ws_size,
                              hipStream_t stream) {
  const float* input  = (const float*)d_in[0];
  const int* qweight  = (const int*)d_in[1];
  const float* absmax = (const float*)d_in[2];
  const float* lora_A = (const float*)d_in[3];
  const float* lora_B = (const float*)d_in[4];
  float* out = (float*)d_out;

  unsigned short* A16  = (unsigned short*)d_ws;                 // 2048*4096 bf16
  unsigned short* B16  = A16 + (size_t)M_DIM * K_DIM;           // 4096*4096 bf16
  unsigned short* lB16 = B16 + (size_t)N_DIM * K_DIM;           // 4096*64
  unsigned short* lA16 = lB16 + (size_t)N_DIM * 64;             // 64*4096
  unsigned short* U16  = lA16 + (size_t)64 * K_DIM;             // 2048*64
  // split-K partials live in d_out (8.4 MB of its 33.5 MB); k_gemm overwrites
  // all of d_out afterwards, so this is race-free and deterministic.
  float* Up = out;

  // fused prep: input/lora_A/lora_B cvt + NF4 dequant (all independent)
  k_prep<<<16896, 256, 0, stream>>>((const float4*)input, (ushort4*)A16,
                                    (const float4*)lora_A, (ushort4*)lA16,
                                    (const float4*)lora_B, (ushort4*)lB16,
                                    qweight, absmax, B16);
  // U partials (split-K), then deterministic reduce -> U16
  k_lora_u<<<256, 256, 0, stream>>>(A16, lA16, Up);
  k_lora_red<<<(M_DIM * 64 / 4) / 256, 256, 0, stream>>>((const float4*)Up,
                                                         (ushort4*)U16);
  // C = [A16 | U] @ [B16 | lB16]^T
  k_gemm<<<256, 512, 0, stream>>>(A16, B16, U16, lB16, out);
}